// Round 3
// baseline (217.563 us; speedup 1.0000x reference)
//
#include <hip/hip_runtime.h>

typedef unsigned long long u64;
typedef unsigned int u32;

#define G 512
#define T 128
#define P 256
#define B 512
#define NROWS 65536   /* G*T */

// ---------------------------------------------------------------------------
// Identity bit layout everywhere: u32 word w of a row covers params
// [32w, 32w+32), bit k = param 32w+k. u64 views pair words little-endian, so
// u64 j covers params [64j, 64j+64). Same layout for rows, pv, codes.
// ---------------------------------------------------------------------------

// Pack both fp32 matrices into bit rows. One thread per output u32.
// rows_u32[(g*T+t)*16 + m*8 + w]  (m=0 psi, m=1 phi) -> per-row record is
// 64 B (8 u64): psi words 0..3, phi words 4..7, matching one s_load_dwordx16.
__global__ __launch_bounds__(256) void pack_big_kernel(
    const float* __restrict__ psi, const float* __restrict__ phi,
    u32* __restrict__ rows)
{
    const unsigned tid = blockIdx.x * 256u + threadIdx.x;  // 0 .. 2^20-1
    const unsigned w = tid & 7u;
    const unsigned r = (tid >> 3) & 65535u;
    const unsigned m = tid >> 19;
    const float* mat = m ? phi : psi;
    const float4* src = (const float4*)(mat + (size_t)r * P + w * 32u);

    float4 f[8];
    #pragma unroll
    for (int s = 0; s < 8; ++s) f[s] = src[s];   // 8 independent loads in flight

    u32 word = 0;
    #pragma unroll
    for (int s = 0; s < 8; ++s) {
        word |= ((__float_as_uint(f[s].x) >> 29) & 1u) << (4 * s + 0);
        word |= ((__float_as_uint(f[s].y) >> 29) & 1u) << (4 * s + 1);
        word |= ((__float_as_uint(f[s].z) >> 29) & 1u) << (4 * s + 2);
        word |= ((__float_as_uint(f[s].w) >> 29) & 1u) << (4 * s + 3);
    }
    rows[(size_t)r * 16u + m * 8u + w] = word;
}

// Pack param_vals (B x P) and the const vectors. 8192 threads.
//   pv_out[b*8 + j]   : params [32j, 32j+32) of batch b
//   codes[g*8 + k]    : k=0..3 psi const bits t in [32k,32k+32); k=4..7 phi
__global__ __launch_bounds__(256) void pack_small_kernel(
    const float* __restrict__ pv, const int* __restrict__ psi_c,
    const int* __restrict__ phi_c, u32* __restrict__ pv_out,
    u32* __restrict__ codes)
{
    const unsigned tid = blockIdx.x * 256u + threadIdx.x;
    if (tid < 4096u) {
        const unsigned b = tid >> 3, j = tid & 7u;
        const float4* src = (const float4*)(pv + (size_t)b * P + j * 32u);
        float4 f[8];
        #pragma unroll
        for (int s = 0; s < 8; ++s) f[s] = src[s];
        u32 word = 0;
        #pragma unroll
        for (int s = 0; s < 8; ++s) {
            word |= ((__float_as_uint(f[s].x) >> 29) & 1u) << (4 * s + 0);
            word |= ((__float_as_uint(f[s].y) >> 29) & 1u) << (4 * s + 1);
            word |= ((__float_as_uint(f[s].z) >> 29) & 1u) << (4 * s + 2);
            word |= ((__float_as_uint(f[s].w) >> 29) & 1u) << (4 * s + 3);
        }
        pv_out[b * 8u + j] = word;
    } else {
        const unsigned t2 = tid - 4096u;
        const unsigned g = t2 >> 3, k = t2 & 7u;
        const int* src = ((k < 4u) ? psi_c : phi_c) + (size_t)g * T + (k & 3u) * 32u;
        const int4* s4 = (const int4*)src;
        u32 word = 0;
        #pragma unroll
        for (int s = 0; s < 8; ++s) {
            int4 c = s4[s];
            word |= ((u32)c.x & 1u) << (4 * s + 0);
            word |= ((u32)c.y & 1u) << (4 * s + 1);
            word |= ((u32)c.z & 1u) << (4 * s + 2);
            word |= ((u32)c.w & 1u) << (4 * s + 3);
        }
        codes[g * 8u + k] = word;
    }
}

// Main compute. Block = (g, b-quarter); thread = (T-half h, local b).
// h = tid>>7 is wave-uniform, so the row pointer stays uniform -> scalar
// s_load_dwordx16 per term. Halves combine through 512 B of LDS.
// grid = G*4 = 2048 blocks of 256 -> 8 blocks/CU, 32 waves/CU.
__global__ __launch_bounds__(256) void pi_main_kernel(
    const u64* __restrict__ rows,   // (g*T+t)*8 : psi u64 0..3, phi 4..7
    const u64* __restrict__ codes,  // g*4 : psi lo, psi hi, phi lo, phi hi
    const u64* __restrict__ pv,     // b*4
    float4*    __restrict__ out)
{
    __shared__ unsigned epart[128];

    const int g   = blockIdx.x >> 2;
    const int q   = blockIdx.x & 3;
    const int tid = threadIdx.x;
    const int h   = tid >> 7;        // wave-uniform T-half
    const int bl  = tid & 127;
    const int b   = q * 128 + bl;

    const u64* v = pv + (size_t)b * 4;
    u64 v0 = v[0], v1 = v[1], v2 = v[2], v3 = v[3];

    u64 pcw = codes[g * 4 + h];       // psi const bits for this half (scalar)
    u64 qcw = codes[g * 4 + 2 + h];

    const u64* r = rows + ((size_t)g * T + (size_t)h * 64) * 8;

    unsigned e = 0;
    #pragma unroll 4
    for (int i = 0; i < 64; ++i, r += 8) {
        u64 ma = (r[0] & v0) ^ (r[1] & v1) ^ (r[2] & v2) ^ (r[3] & v3);
        u64 mb = (r[4] & v0) ^ (r[5] & v1) ^ (r[6] & v2) ^ (r[7] & v3);
        unsigned pa = (unsigned)__popcll(ma) ^ (unsigned)(pcw >> i);
        unsigned pb = (unsigned)__popcll(mb) ^ (unsigned)(qcw >> i);
        e ^= pa & pb;                 // only bit 0 meaningful
    }

    if (h) epart[bl] = e;
    __syncthreads();
    if (!h) {
        e ^= epart[bl];
        float s = 1.0f - 2.0f * (float)(e & 1u);   // (-1)^parity
        out[(size_t)b * G + g] = make_float4(s, 0.0f, 0.0f, 0.0f);
    }
}

extern "C" void kernel_launch(void* const* d_in, const int* in_sizes, int n_in,
                              void* d_out, int out_size, void* d_ws, size_t ws_size,
                              hipStream_t stream) {
    const int*   psi_const  = (const int*)  d_in[0];
    const float* psi_params = (const float*)d_in[1];
    const int*   phi_const  = (const int*)  d_in[2];
    const float* phi_params = (const float*)d_in[3];
    const float* param_vals = (const float*)d_in[4];

    // Workspace (u32 elements): rows 1,048,576 (4 MiB) | codes 4096 | pv 4096
    u32* rows_u32  = (u32*)d_ws;
    u32* codes_u32 = rows_u32 + (size_t)NROWS * 16;
    u32* pv_u32    = codes_u32 + (size_t)G * 8;

    pack_big_kernel  <<<4096, 256, 0, stream>>>(psi_params, phi_params, rows_u32);
    pack_small_kernel<<<32,   256, 0, stream>>>(param_vals, psi_const, phi_const,
                                                pv_u32, codes_u32);
    pi_main_kernel   <<<G * 4, 256, 0, stream>>>((const u64*)rows_u32,
                                                 (const u64*)codes_u32,
                                                 (const u64*)pv_u32,
                                                 (float4*)d_out);
}

// Round 4
// 191.175 us; speedup vs baseline: 1.1380x; 1.1380x over previous
//
#include <hip/hip_runtime.h>

typedef unsigned long long u64;
typedef unsigned int u32;

#define G 512
#define T 128
#define P 256
#define B 512
#define NROWS 65536   /* G*T */
#define PAD 33        /* floats per 32-float group in LDS (bank-conflict pad) */

// ---------------------------------------------------------------------------
// Identity bit layout: u32 word w of a row covers params [32w, 32w+32),
// bit k = param 32w+k. u64 view: u64 j = params [64j, 64j+64). Same layout
// for rows, pv, codes. Row record = 16 u32 (64 B): psi words 0..7, phi 8..15.
// ---------------------------------------------------------------------------

// Pack both fp32 matrices via LDS transpose.
// Block handles 16 full records (16 rows x 2 matrices = 32 KB of floats).
// Phase 1: coalesced global float4 loads -> padded LDS.
// Phase 2: thread t packs one u32 word from 32 LDS floats; coalesced store.
__global__ __launch_bounds__(256) void pack_big_kernel(
    const float* __restrict__ psi, const float* __restrict__ phi,
    u32* __restrict__ rows)
{
    __shared__ float lds[256 * PAD];
    const int tid = threadIdx.x;
    const int r0  = blockIdx.x * 16;          // records [r0, r0+16)

    // Phase 1: waves 0,1 load psi rows, waves 2,3 load phi rows (wave-uniform m)
    {
        const int m  = tid >> 7;
        const int t2 = tid & 127;
        const float* src = (m ? phi : psi) + (size_t)r0 * P;
        #pragma unroll
        for (int j = 0; j < 8; ++j) {
            int fi = (j * 128 + t2) * 4;      // float index 0..4092, lane-contiguous
            float4 f = *(const float4*)(src + fi);
            float* d = &lds[(m * 128 + (fi >> 5)) * PAD + (fi & 31)];
            d[0] = f.x; d[1] = f.y; d[2] = f.z; d[3] = f.w;
        }
    }
    __syncthreads();

    // Phase 2: rec = tid>>4, inner = tid&15 (m = inner>>3, w = inner&7)
    {
        const int rec = tid >> 4, inner = tid & 15;
        const int grp = ((inner >> 3) * 128) + rec * 8 + (inner & 7);
        const float* s = &lds[grp * PAD];
        u32 word = 0;
        #pragma unroll
        for (int k = 0; k < 32; ++k)
            word |= ((__float_as_uint(s[k]) >> 29) & 1u) << k;   // 1.0f -> bit29
        rows[(size_t)(r0 + rec) * 16 + inner] = word;            // coalesced
    }
}

// Pack param_vals (B x P) and const vectors. 8192 threads.
//   pv_out[b*8 + j] : params [32j, 32j+32) of batch b
//   codes[g*8 + k]  : k=0..3 psi const bits t in [32k,32k+32); k=4..7 phi
__global__ __launch_bounds__(256) void pack_small_kernel(
    const float* __restrict__ pv, const int* __restrict__ psi_c,
    const int* __restrict__ phi_c, u32* __restrict__ pv_out,
    u32* __restrict__ codes)
{
    const unsigned tid = blockIdx.x * 256u + threadIdx.x;
    if (tid < 4096u) {
        const unsigned b = tid >> 3, j = tid & 7u;
        const float4* src = (const float4*)(pv + (size_t)b * P + j * 32u);
        float4 f[8];
        #pragma unroll
        for (int s = 0; s < 8; ++s) f[s] = src[s];
        u32 word = 0;
        #pragma unroll
        for (int s = 0; s < 8; ++s) {
            word |= ((__float_as_uint(f[s].x) >> 29) & 1u) << (4 * s + 0);
            word |= ((__float_as_uint(f[s].y) >> 29) & 1u) << (4 * s + 1);
            word |= ((__float_as_uint(f[s].z) >> 29) & 1u) << (4 * s + 2);
            word |= ((__float_as_uint(f[s].w) >> 29) & 1u) << (4 * s + 3);
        }
        pv_out[b * 8u + j] = word;
    } else {
        const unsigned t2 = tid - 4096u;
        const unsigned g = t2 >> 3, k = t2 & 7u;
        const int* src = ((k < 4u) ? psi_c : phi_c) + (size_t)g * T + (k & 3u) * 32u;
        const int4* s4 = (const int4*)src;
        u32 word = 0;
        #pragma unroll
        for (int s = 0; s < 8; ++s) {
            int4 c = s4[s];
            word |= ((u32)c.x & 1u) << (4 * s + 0);
            word |= ((u32)c.y & 1u) << (4 * s + 1);
            word |= ((u32)c.z & 1u) << (4 * s + 2);
            word |= ((u32)c.w & 1u) << (4 * s + 3);
        }
        codes[g * 8u + k] = word;
    }
}

// Main compute. g derives ONLY from blockIdx -> row pointer is provably
// uniform -> scalar s_load_dwordx16 per term. Two interleaved term streams
// (t, t+64) give ~8 independent scalar loads per unroll-4 window to hide
// SMEM latency. grid = G*2 blocks of 256; thread owns one (b, g).
__global__ __launch_bounds__(256) void pi_main_kernel(
    const u64* __restrict__ rows,   // (g*T+t)*8 : psi u64 0..3, phi 4..7
    const u64* __restrict__ codes,  // g*4 : psi lo, psi hi, phi lo, phi hi
    const u64* __restrict__ pv,     // b*4
    float4*    __restrict__ out)
{
    const int g = blockIdx.x >> 1;
    const int b = ((blockIdx.x & 1) << 8) | threadIdx.x;

    const u64* v = pv + (size_t)b * 4;
    u64 v0 = v[0], v1 = v[1], v2 = v[2], v3 = v[3];

    u64 pc0 = codes[g * 4 + 0], pc1 = codes[g * 4 + 1];   // uniform (scalar)
    u64 qc0 = codes[g * 4 + 2], qc1 = codes[g * 4 + 3];

    const u64* rA = rows + (size_t)g * (T * 8);           // terms 0..63
    const u64* rB = rA + 64 * 8;                          // terms 64..127

    unsigned e0 = 0, e1 = 0;
    #pragma unroll 4
    for (int t = 0; t < 64; ++t, rA += 8, rB += 8) {
        u64 ma = (rA[0] & v0) ^ (rA[1] & v1) ^ (rA[2] & v2) ^ (rA[3] & v3);
        u64 mb = (rA[4] & v0) ^ (rA[5] & v1) ^ (rA[6] & v2) ^ (rA[7] & v3);
        e0 ^= ((unsigned)__popcll(ma) ^ (unsigned)(pc0 >> t))
            & ((unsigned)__popcll(mb) ^ (unsigned)(qc0 >> t));
        u64 mc = (rB[0] & v0) ^ (rB[1] & v1) ^ (rB[2] & v2) ^ (rB[3] & v3);
        u64 md = (rB[4] & v0) ^ (rB[5] & v1) ^ (rB[6] & v2) ^ (rB[7] & v3);
        e1 ^= ((unsigned)__popcll(mc) ^ (unsigned)(pc1 >> t))
            & ((unsigned)__popcll(md) ^ (unsigned)(qc1 >> t));
    }
    unsigned e = (e0 ^ e1) & 1u;

    float s = 1.0f - 2.0f * (float)e;   // (-1)^parity
    out[(size_t)b * G + g] = make_float4(s, 0.0f, 0.0f, 0.0f);
}

extern "C" void kernel_launch(void* const* d_in, const int* in_sizes, int n_in,
                              void* d_out, int out_size, void* d_ws, size_t ws_size,
                              hipStream_t stream) {
    const int*   psi_const  = (const int*)  d_in[0];
    const float* psi_params = (const float*)d_in[1];
    const int*   phi_const  = (const int*)  d_in[2];
    const float* phi_params = (const float*)d_in[3];
    const float* param_vals = (const float*)d_in[4];

    // Workspace (u32 elements): rows 1,048,576 (4 MiB) | codes 4096 | pv 4096
    u32* rows_u32  = (u32*)d_ws;
    u32* codes_u32 = rows_u32 + (size_t)NROWS * 16;
    u32* pv_u32    = codes_u32 + (size_t)G * 8;

    pack_big_kernel  <<<NROWS / 16, 256, 0, stream>>>(psi_params, phi_params,
                                                      rows_u32);
    pack_small_kernel<<<32, 256, 0, stream>>>(param_vals, psi_const, phi_const,
                                              pv_u32, codes_u32);
    pi_main_kernel   <<<G * 2, 256, 0, stream>>>((const u64*)rows_u32,
                                                 (const u64*)codes_u32,
                                                 (const u64*)pv_u32,
                                                 (float4*)d_out);
}

// Round 5
// 190.115 us; speedup vs baseline: 1.1444x; 1.0056x over previous
//
#include <hip/hip_runtime.h>

typedef unsigned long long u64;
typedef unsigned int u32;

#define G 512
#define T 128
#define P 256
#define B 512
#define NROWS 65536      /* G*T */
#define BIGBLOCKS 2048   /* big-pack blocks; 8 records per wave */

struct __align__(16) U64x2 { u64 x, y; };

// ---------------------------------------------------------------------------
// Ballot bit layout (used identically for rows, pv, codes-free dims):
//   word j (j=0..3) of a 256-param row: bit L = param[4L + j].
// Parity of AND is invariant under any shared bit permutation.
// Row record = 8 u64 (64 B): psi words 0..3, phi words 4..7.
// codes[g*4 + {0,1,2,3}] = psi lo/hi, phi lo/hi term bits (identity in t).
// ---------------------------------------------------------------------------

__device__ __forceinline__ void store_rec8(u64* dst, u64 w0, u64 w1, u64 w2,
                                           u64 w3, u64 w4, u64 w5, u64 w6, u64 w7)
{
    U64x2* d = (U64x2*)dst;
    U64x2 a; a.x = w0; a.y = w1;
    U64x2 b; b.x = w2; b.y = w3;
    U64x2 c; c.x = w4; c.y = w5;
    U64x2 e; e.x = w6; e.y = w7;
    d[0] = a; d[1] = b; d[2] = c; d[3] = e;
}

// One kernel packs everything. Blocks [0,2048): matrices (8 records/wave,
// 16 hoisted 1-KB coalesced loads in flight before any ballot). Blocks
// [2048,2080): param_vals + const codes.
__global__ __launch_bounds__(256) void pack_all_kernel(
    const float* __restrict__ psi, const float* __restrict__ phi,
    const int* __restrict__ psi_c, const int* __restrict__ phi_c,
    const float* __restrict__ pvf,
    u64* __restrict__ rows, u64* __restrict__ codes, u64* __restrict__ pv)
{
    const int lane = threadIdx.x & 63;
    const int wave = threadIdx.x >> 6;

    if (blockIdx.x < BIGBLOCKS) {
        const int wid = blockIdx.x * 4 + wave;   // 0..8191
        const int r0  = wid * 8;                 // records [r0, r0+8)
        float4 A[8], Bf[8];
        #pragma unroll
        for (int k = 0; k < 8; ++k)
            A[k]  = *(const float4*)(psi + (size_t)(r0 + k) * P + lane * 4);
        #pragma unroll
        for (int k = 0; k < 8; ++k)
            Bf[k] = *(const float4*)(phi + (size_t)(r0 + k) * P + lane * 4);
        #pragma unroll
        for (int k = 0; k < 8; ++k) {
            u64 w0 = __ballot(A[k].x  != 0.0f);
            u64 w1 = __ballot(A[k].y  != 0.0f);
            u64 w2 = __ballot(A[k].z  != 0.0f);
            u64 w3 = __ballot(A[k].w  != 0.0f);
            u64 w4 = __ballot(Bf[k].x != 0.0f);
            u64 w5 = __ballot(Bf[k].y != 0.0f);
            u64 w6 = __ballot(Bf[k].z != 0.0f);
            u64 w7 = __ballot(Bf[k].w != 0.0f);
            if (lane == 0)
                store_rec8(rows + (size_t)(r0 + k) * 8,
                           w0, w1, w2, w3, w4, w5, w6, w7);
        }
    } else {
        const int wid2 = (blockIdx.x - BIGBLOCKS) * 4 + wave;  // 0..127
        float4 pf[4];
        int ip[8], iq[8];
        #pragma unroll
        for (int i = 0; i < 4; ++i)
            pf[i] = *(const float4*)(pvf + (size_t)(wid2 * 4 + i) * P + lane * 4);
        #pragma unroll
        for (int i = 0; i < 4; ++i) {
            int g = wid2 * 4 + i;
            ip[2 * i]     = psi_c[g * T + lane];
            ip[2 * i + 1] = psi_c[g * T + 64 + lane];
            iq[2 * i]     = phi_c[g * T + lane];
            iq[2 * i + 1] = phi_c[g * T + 64 + lane];
        }
        #pragma unroll
        for (int i = 0; i < 4; ++i) {
            int bt = wid2 * 4 + i;
            u64 w0 = __ballot(pf[i].x != 0.0f);
            u64 w1 = __ballot(pf[i].y != 0.0f);
            u64 w2 = __ballot(pf[i].z != 0.0f);
            u64 w3 = __ballot(pf[i].w != 0.0f);
            if (lane == 0) {
                U64x2* d = (U64x2*)(pv + (size_t)bt * 4);
                U64x2 a; a.x = w0; a.y = w1;
                U64x2 b; b.x = w2; b.y = w3;
                d[0] = a; d[1] = b;
            }
        }
        #pragma unroll
        for (int i = 0; i < 4; ++i) {
            int g = wid2 * 4 + i;
            u64 a0 = __ballot(ip[2 * i]     != 0);
            u64 a1 = __ballot(ip[2 * i + 1] != 0);
            u64 b0 = __ballot(iq[2 * i]     != 0);
            u64 b1 = __ballot(iq[2 * i + 1] != 0);
            if (lane == 0) {
                U64x2* d = (U64x2*)(codes + (size_t)g * 4);
                U64x2 a; a.x = a0; a.y = a1;
                U64x2 b; b.x = b0; b.y = b1;
                d[0] = a; d[1] = b;
            }
        }
    }
}

// Main compute. g derives ONLY from blockIdx -> row pointer provably uniform
// -> scalar s_load_dwordx16 per term. Two interleaved term streams (t, t+64),
// unroll 4 -> ~8 independent scalar loads in the window. Thread owns (b, g).
__global__ __launch_bounds__(256) void pi_main_kernel(
    const u64* __restrict__ rows,   // (g*T+t)*8 : psi u64 0..3, phi 4..7
    const u64* __restrict__ codes,  // g*4 : psi lo, psi hi, phi lo, phi hi
    const u64* __restrict__ pv,     // b*4
    float4*    __restrict__ out)
{
    const int g = blockIdx.x >> 1;
    const int b = ((blockIdx.x & 1) << 8) | threadIdx.x;

    const u64* v = pv + (size_t)b * 4;
    u64 v0 = v[0], v1 = v[1], v2 = v[2], v3 = v[3];

    u64 pc0 = codes[g * 4 + 0], pc1 = codes[g * 4 + 1];   // uniform (scalar)
    u64 qc0 = codes[g * 4 + 2], qc1 = codes[g * 4 + 3];

    const u64* rA = rows + (size_t)g * (T * 8);           // terms 0..63
    const u64* rB = rA + 64 * 8;                          // terms 64..127

    unsigned e0 = 0, e1 = 0;
    #pragma unroll 4
    for (int t = 0; t < 64; ++t, rA += 8, rB += 8) {
        u64 ma = (rA[0] & v0) ^ (rA[1] & v1) ^ (rA[2] & v2) ^ (rA[3] & v3);
        u64 mb = (rA[4] & v0) ^ (rA[5] & v1) ^ (rA[6] & v2) ^ (rA[7] & v3);
        e0 ^= ((unsigned)__popcll(ma) ^ (unsigned)(pc0 >> t))
            & ((unsigned)__popcll(mb) ^ (unsigned)(qc0 >> t));
        u64 mc = (rB[0] & v0) ^ (rB[1] & v1) ^ (rB[2] & v2) ^ (rB[3] & v3);
        u64 md = (rB[4] & v0) ^ (rB[5] & v1) ^ (rB[6] & v2) ^ (rB[7] & v3);
        e1 ^= ((unsigned)__popcll(mc) ^ (unsigned)(pc1 >> t))
            & ((unsigned)__popcll(md) ^ (unsigned)(qc1 >> t));
    }
    unsigned e = (e0 ^ e1) & 1u;

    float s = 1.0f - 2.0f * (float)e;   // (-1)^parity
    out[(size_t)b * G + g] = make_float4(s, 0.0f, 0.0f, 0.0f);
}

extern "C" void kernel_launch(void* const* d_in, const int* in_sizes, int n_in,
                              void* d_out, int out_size, void* d_ws, size_t ws_size,
                              hipStream_t stream) {
    const int*   psi_const  = (const int*)  d_in[0];
    const float* psi_params = (const float*)d_in[1];
    const int*   phi_const  = (const int*)  d_in[2];
    const float* phi_params = (const float*)d_in[3];
    const float* param_vals = (const float*)d_in[4];

    // Workspace (u64 elements): rows 524288 (4 MiB) | codes 2048 | pv 2048
    u64* rows  = (u64*)d_ws;
    u64* codes = rows + (size_t)NROWS * 8;
    u64* pv    = codes + (size_t)G * 4;

    pack_all_kernel<<<BIGBLOCKS + 32, 256, 0, stream>>>(
        psi_params, phi_params, psi_const, phi_const, param_vals,
        rows, codes, pv);
    pi_main_kernel<<<G * 2, 256, 0, stream>>>(rows, codes, pv, (float4*)d_out);
}